// Round 18
// baseline (51.918 us; speedup 1.0000x reference)
//
#include <hip/hip_runtime.h>

typedef __attribute__((ext_vector_type(8))) __bf16 bf16x8;
typedef __attribute__((ext_vector_type(4))) float f32x4;
typedef __attribute__((ext_vector_type(2))) float f32x2;

#define DI 512
#define DO 512
#define XROW (128 * DI)
#define OROW (128 * DO)
#define BK 64                // 8 K-iterations: halve the per-iter fixed cost
#define BOFF 16384           // buf: A bf16 [128][64] 16 KB | B bf16 [128][64] 16 KB
#define BUFSZ 32768

#define LGKM0()  asm volatile("s_waitcnt lgkmcnt(0)" ::: "memory")
#define SBAR()   __builtin_amdgcn_s_barrier()
#define SCHED0() __builtin_amdgcn_sched_barrier(0)

// R6..R16 lesson: per-iteration stage+wait+barrier overhead (~5K cyc) is the
// invariant cost; nothing inside the iteration moves it. So have fewer
// iterations. BK=64 with acc=32 (the R7 spill-killer was acc=64 + live
// staging): demand = 32 acc + 32 staging + 8 bfr + ~25 misc ~= 100 <= 128.
__global__ __launch_bounds__(512, 4)
void nlinear_mfma(const float* __restrict__ xp, const float* __restrict__ wp,
                  const float* __restrict__ bp, float* __restrict__ op) {
  // XCD swizzle: 1024 blocks, 128/XCD; one n's 8 tiles stay on one XCD
  int blk = blockIdx.x;
  int L = ((blk & 7) << 7) + (blk >> 3);
  int n = L >> 3, mt = (L >> 2) & 1, ot = L & 3;
  int mBase = mt << 7, oBase = ot << 7;      // block tile: 128m x 128o

  __shared__ char lds[2 * BUFSZ];            // 64 KB -> 2 blocks/CU resident

  int tid = threadIdx.x, lane = tid & 63, wid = tid >> 6;
  int wm = (wid >> 2) << 6, wn = (wid & 3) << 5;   // wave tile 64m x 32o
  int l16 = lane & 15, l4 = lane >> 4;

  // Both LDS tiles [128 rows][64 k] bf16 = 128 B/row = 8 x 16B slots.
  // Swizzle: phys_slot = slot ^ ((row>>1)&7) on every write and read.
  // All access patterns below spread uniformly -> ~2-way max (free, m136).

  // A staging: thread t -> m-row t>>2, k-quarter (t&3)*16 (16 floats).
  // 4 x f32x4 loads; 2 x b128 writes at slots {2q, 2q+1}.
  int arow = tid >> 2, aq = tid & 3;
  const float* aSrc = xp + (size_t)(mBase + arow) * XROW + n * DI + aq * 16;
  int aswz = ((arow >> 1) & 7) << 4;
  int aWr0 = arow * 128 + (((aq << 1))     << 4 ^ aswz);
  int aWr1 = arow * 128 + (((aq << 1) | 1) << 4 ^ aswz);

  f32x4 aRv[4];
  auto loadA = [&](int kt) {
    #pragma unroll
    for (int i = 0; i < 4; ++i)
      aRv[i] = *(const f32x4*)(aSrc + kt * BK + i * 4);
  };
  auto writeA = [&](int bufOff) {
    bf16x8 v0, v1;
    #pragma unroll
    for (int e = 0; e < 8; ++e) {
      v0[e] = (__bf16)aRv[e >> 2][e & 3];
      v1[e] = (__bf16)aRv[2 + (e >> 2)][e & 3];
    }
    *(bf16x8*)(lds + bufOff + aWr0) = v0;
    *(bf16x8*)(lds + bufOff + aWr1) = v1;
  };

  // B staging: thread t -> o-pair {2*(t&63), +1}, k-oct (t>>6)*8 (8 k).
  // 8 x f32x2 loads (512B/wave per k-row); 2 x b128 writes (slot = wid).
  int bo2 = (tid & 63) << 1, boct = tid >> 6;      // boct == wid, uniform
  const float* bSrc = wp + ((size_t)n * DI + (boct << 3)) * DO + oBase + bo2;
  int bWr0 = BOFF + (bo2)     * 128 + ((boct ^ (((bo2)     >> 1) & 7)) << 4);
  int bWr1 = BOFF + (bo2 + 1) * 128 + ((boct ^ (((bo2 + 1) >> 1) & 7)) << 4);

  f32x2 bRv[8];
  auto loadB = [&](int kt) {
    #pragma unroll
    for (int j = 0; j < 8; ++j)
      bRv[j] = *(const f32x2*)(bSrc + (size_t)(kt * BK + j) * DO);
  };
  auto writeB = [&](int bufOff) {
    bf16x8 v0, v1;
    #pragma unroll
    for (int j = 0; j < 8; ++j) { v0[j] = (__bf16)bRv[j].x; v1[j] = (__bf16)bRv[j].y; }
    *(bf16x8*)(lds + bufOff + bWr0) = v0;
    *(bf16x8*)(lds + bufOff + bWr1) = v1;
  };

  f32x4 acc[4][2];
  #pragma unroll
  for (int i = 0; i < 4; ++i)
    #pragma unroll
    for (int j = 0; j < 2; ++j)
      acc[i][j] = f32x4{0.f, 0.f, 0.f, 0.f};

  // compute: 2 k-steps x (2 bfr + 4 af b128, 8 MFMA) = 16 MFMA / wave-iter
  auto compute = [&](int bufOff) {
    #pragma unroll
    for (int ks = 0; ks < 2; ++ks) {
      bf16x8 bfr[2];
      #pragma unroll
      for (int j = 0; j < 2; ++j) {
        int row = wn + j * 16 + l16;
        int slot = (ks * 4 + l4) ^ ((row >> 1) & 7);
        bfr[j] = *(const bf16x8*)(lds + bufOff + BOFF + row * 128 + slot * 16);
      }
      #pragma unroll
      for (int i = 0; i < 4; ++i) {
        int row = wm + i * 16 + l16;
        int slot = (ks * 4 + l4) ^ ((row >> 1) & 7);
        bf16x8 af = *(const bf16x8*)(lds + bufOff + row * 128 + slot * 16);
        acc[i][0] = __builtin_amdgcn_mfma_f32_16x16x32_bf16(af, bfr[0], acc[i][0], 0, 0, 0);
        acc[i][1] = __builtin_amdgcn_mfma_f32_16x16x32_bf16(af, bfr[1], acc[i][1], 0, 0, 0);
      }
    }
  };

  float bi[2];
  #pragma unroll
  for (int j = 0; j < 2; ++j)
    bi[j] = bp[n * DO + oBase + wn + j * 16 + l16];

  // ---- prologue: buf0 staged; tile1 loads in flight across the barrier ----
  loadA(0); loadB(0);
  writeA(0); writeB(0);        // auto-wait tile0 regs
  loadA(1); loadB(1);
  SCHED0(); LGKM0(); SBAR(); SCHED0();

  // iter kt (8 total): writes wait 1-iter-aged regs; loads for kt+2 issued
  // between the writes so vmcnt stays counted (writeA->vmcnt(8),
  // writeB->vmcnt(4); never a full mid-loop drain). One barrier per iter.
  for (int kt = 0; kt < 8; ++kt) {
    int cur = (kt & 1) * BUFSZ, nxt = cur ^ BUFSZ;
    if (kt < 7) {
      writeA(nxt);             // vmcnt(8): retire A(kt+1), keep B(kt+1)
      if (kt < 6) loadA(kt + 2);
      writeB(nxt);             // vmcnt(4): retire B(kt+1), keep A(kt+2)
      if (kt < 6) loadB(kt + 2);
      SCHED0();
    }
    compute(cur);
    if (kt < 7) { SCHED0(); LGKM0(); SBAR(); SCHED0(); }
  }

  // epilogue: D layout col = lane&15, row = (lane>>4)*4 + r (m89-verified)
  #pragma unroll
  for (int i = 0; i < 4; ++i) {
    #pragma unroll
    for (int j = 0; j < 2; ++j) {
      #pragma unroll
      for (int r = 0; r < 4; ++r) {
        int m = mBase + wm + i * 16 + l4 * 4 + r;
        int o = oBase + wn + j * 16 + l16;
        op[(size_t)m * OROW + n * DO + o] = acc[i][j][r] + bi[j];
      }
    }
  }
}

extern "C" void kernel_launch(void* const* d_in, const int* in_sizes, int n_in,
                              void* d_out, int out_size, void* d_ws, size_t ws_size,
                              hipStream_t stream) {
  const float* x = (const float*)d_in[0];
  const float* w = (const float*)d_in[1];
  const float* b = (const float*)d_in[2];
  float* o = (float*)d_out;
  hipLaunchKernelGGL(nlinear_mfma, dim3(1024), dim3(512), 0, stream, x, w, b, o);
}

// Round 19
// 45.617 us; speedup vs baseline: 1.1381x; 1.1381x over previous
//
#include <hip/hip_runtime.h>

typedef __attribute__((ext_vector_type(8))) __bf16 bf16x8;
typedef __attribute__((ext_vector_type(4))) float f32x4;
typedef __attribute__((ext_vector_type(2))) float f32x2;

#define DI 512
#define DO 512
#define XROW (128 * DI)
#define OROW (128 * DO)
#define BK 32
#define BOFF 16384          // A: fp32 [128][32] = 16 KB | B: bf16 [256][32] = 16 KB
#define BUFSZ 32768

#define VMCNT(n) asm volatile("s_waitcnt vmcnt(" #n ")" ::: "memory")
#define LGKM0()  asm volatile("s_waitcnt lgkmcnt(0)" ::: "memory")
#define SBAR()   __builtin_amdgcn_s_barrier()
#define SCHED0() __builtin_amdgcn_sched_barrier(0)

// R10 (45.5 us, best) + co-resident-pair dephasing ONLY:
//  - odd (blk>>8) blocks sleep ~3.4K cyc at start (half an iteration period)
//  - and rotate their K-loop start by 8 tiles (decorrelate memory bursts)
// Theory: the 2 blocks/CU launch in lockstep and stay phase-locked, so
// inter-domain TLP never fills the per-iteration wait phases.
__global__ __launch_bounds__(512, 4)
void nlinear_mfma(const float* __restrict__ xp, const float* __restrict__ wp,
                  const float* __restrict__ bp, float* __restrict__ op) {
  int blk = blockIdx.x;
  int par = (blk >> 8) & 1;          // co-resident pair (blk, blk+256)
  if (par) __builtin_amdgcn_s_sleep(53);   // ~53*64 = 3.4K cyc time stagger

  int koff = par << 3;               // K-phase rotation (reduction reorder OK)
  #define KT(k) ((((k) + koff)) & 15)

  // XCD swizzle: 512 blocks, 64 per XCD; the 4 tiles of one n stay together
  int L = ((blk & 7) << 6) + (blk >> 3);
  int n = L >> 2, mt = (L >> 1) & 1, ot = L & 1;
  int mBase = mt << 7, oBase = ot << 8;      // block tile: 128m x 256o

  __shared__ char lds[2 * BUFSZ];            // 64 KB

  int tid = threadIdx.x, lane = tid & 63, wid = tid >> 6;
  int wm = (wid >> 2) << 6, wn = (wid & 3) << 6;   // wave tile 64m x 64o
  int l16 = lane & 15, l4 = lane >> 4;

  // A DMA (R8-R10 proven): wave w rows w*16..+16, 2 instrs x 1KB; source
  // pre-swizzled slot g = (lane&7) ^ ((row>>1)&7), LDS dest linear (rule #21).
  unsigned aOff[2];
  #pragma unroll
  for (int i = 0; i < 2; ++i) {
    int r0 = (wid << 4) + (i << 3);
    int row = r0 + (lane >> 3);
    int g = (lane & 7) ^ ((row >> 1) & 7);
    aOff[i] = (unsigned)(((mBase + row) * XROW + n * DI) * 4 + g * 16);
  }
  auto gloadA = [&](int bufOff, int kt) {
    #pragma unroll
    for (int i = 0; i < 2; ++i) {
      int r0 = (wid << 4) + (i << 3);
      __builtin_amdgcn_global_load_lds(
          (const __attribute__((address_space(1))) void*)
              ((const char*)xp + aOff[i] + (unsigned)(kt * 128)),
          (__attribute__((address_space(3))) void*)(lds + bufOff + r0 * 128),
          16, 0, 0);
    }
  };

  // B staging (R10-proven): thread t -> o-pair {2*(t&127), +1}, k-range
  // kq*8..+8; 8 x f32x2 loads (512B/wave per k-row), 2 x b128 writes.
  int bo2 = (tid & 127) << 1, kq = tid >> 7;
  const float* bSrc = wp + ((size_t)n * DI + (kq << 3)) * DO + oBase + bo2;
  int bWr0 = BOFF + (bo2)     * 64 + ((kq ^ ((bo2 >> 1) & 3)) << 4);
  int bWr1 = BOFF + (bo2 + 1) * 64 + ((kq ^ ((bo2 >> 1) & 3)) << 4);

  f32x2 bRv[8];
  auto loadB = [&](int kt) {
    #pragma unroll
    for (int j = 0; j < 8; ++j)
      bRv[j] = *(const f32x2*)(bSrc + (size_t)(kt * BK + j) * DO);
  };
  auto writeB = [&](int bufOff) {
    bf16x8 v0, v1;
    #pragma unroll
    for (int j = 0; j < 8; ++j) { v0[j] = (__bf16)bRv[j].x; v1[j] = (__bf16)bRv[j].y; }
    *(bf16x8*)(lds + bufOff + bWr0) = v0;
    *(bf16x8*)(lds + bufOff + bWr1) = v1;
  };

  f32x4 acc[4][4];
  #pragma unroll
  for (int i = 0; i < 4; ++i)
    #pragma unroll
    for (int j = 0; j < 4; ++j)
      acc[i][j] = f32x4{0.f, 0.f, 0.f, 0.f};

  bf16x8 af[4];
  auto loadAfrags = [&](int bufOff) {
    #pragma unroll
    for (int i = 0; i < 4; ++i) {
      int row = wm + i * 16 + l16;
      int v7 = (row >> 1) & 7;
      const char* rb = lds + bufOff + row * 128;
      f32x4 lo = *(const f32x4*)(rb + ((((l4 << 1))     ^ v7) << 4));
      f32x4 hi = *(const f32x4*)(rb + ((((l4 << 1) | 1) ^ v7) << 4));
      af[i][0] = (__bf16)lo.x; af[i][1] = (__bf16)lo.y;
      af[i][2] = (__bf16)lo.z; af[i][3] = (__bf16)lo.w;
      af[i][4] = (__bf16)hi.x; af[i][5] = (__bf16)hi.y;
      af[i][6] = (__bf16)hi.z; af[i][7] = (__bf16)hi.w;
    }
  };
  auto computeJ = [&](int bufOff, int j) {
    int row = wn + j * 16 + l16;
    int slot = l4 ^ ((row >> 1) & 3);
    bf16x8 bfr = *(const bf16x8*)(lds + bufOff + BOFF + row * 64 + slot * 16);
    #pragma unroll
    for (int i = 0; i < 4; ++i)
      acc[i][j] = __builtin_amdgcn_mfma_f32_16x16x32_bf16(af[i], bfr, acc[i][j], 0, 0, 0);
  };

  float bi[4];
  #pragma unroll
  for (int j = 0; j < 4; ++j)
    bi[j] = bp[n * DO + oBase + wn + j * 16 + l16];

  // ---- prologue: tile KT(0) staged; B(KT(1)) in flight across barrier ----
  gloadA(0, KT(0));        // A first tile (oldest)
  loadB(KT(0));
  writeB(0);               // waits B regs -> in-order retires A too
  loadB(KT(1));
  SCHED0(); LGKM0(); SBAR(); SCHED0();

  // iter kt: J0,J1 from cur; stage tile kt+1 (A-DMA + B-write) + issue
  // B(kt+2); J2,J3; VMCNT(8) retires A(kt+1), keeps B(kt+2) in flight.
  for (int kt = 0; kt < 14; ++kt) {
    int curOff = (kt & 1) * BUFSZ, nxtOff = curOff ^ BUFSZ;
    loadAfrags(curOff);
    computeJ(curOff, 0);
    computeJ(curOff, 1);
    gloadA(nxtOff, KT(kt + 1));  // issue early: full half-iter to land
    writeB(nxtOff);              // B(kt+1) regs aged ~1 iter
    loadB(KT(kt + 2));
    SCHED0();
    computeJ(curOff, 2);
    computeJ(curOff, 3);
    SCHED0();
    VMCNT(8);
    LGKM0(); SBAR(); SCHED0();
  }
  // kt=14: stage tile 15, no more B loads
  {
    loadAfrags(0);
    computeJ(0, 0); computeJ(0, 1);
    gloadA(BUFSZ, KT(15));
    writeB(BUFSZ);
    SCHED0();
    computeJ(0, 2); computeJ(0, 3);
    SCHED0();
    VMCNT(0);
    LGKM0(); SBAR(); SCHED0();
  }
  // kt=15
  loadAfrags(BUFSZ);
  computeJ(BUFSZ, 0); computeJ(BUFSZ, 1);
  computeJ(BUFSZ, 2); computeJ(BUFSZ, 3);

  // epilogue: D layout col = lane&15, row = (lane>>4)*4 + r (m89-verified)
  #pragma unroll
  for (int i = 0; i < 4; ++i) {
    #pragma unroll
    for (int j = 0; j < 4; ++j) {
      #pragma unroll
      for (int r = 0; r < 4; ++r) {
        int m = mBase + wm + i * 16 + l4 * 4 + r;
        int o = oBase + wn + j * 16 + l16;
        op[(size_t)m * OROW + n * DO + o] = acc[i][j][r] + bi[j];
      }
    }
  }
  #undef KT
}

extern "C" void kernel_launch(void* const* d_in, const int* in_sizes, int n_in,
                              void* d_out, int out_size, void* d_ws, size_t ws_size,
                              hipStream_t stream) {
  const float* x = (const float*)d_in[0];
  const float* w = (const float*)d_in[1];
  const float* b = (const float*)d_in[2];
  float* o = (float*)d_out;
  hipLaunchKernelGGL(nlinear_mfma, dim3(512), dim3(512), 0, stream, x, w, b, o);
}